// Round 5
// baseline (74.367 us; speedup 1.0000x reference)
//
#include <hip/hip_runtime.h>

// SConv2d with MAJ3 tree reduction.
// x: (8, 27, 32, 32) f32, w: (27, 27, 3, 3) f32 -> out: (8, 27, 32, 32) f32.
// s-domain trick: (x+1)/2 ... 2r-1 cancels between tree levels; convert once
// at the leaves (s = (0.5*x)*w + 0.5, x prescaled) and once at the root.
//
// R4: 9-way channel split (wave = (c3,c2) digit pair, 3 channels each;
// combine over c2 then c3 in phase 2 -> identical tree association).
// 4 px/thread with aligned b128+b64 LDS reads (1.5 reads/px, was 3).
// 864 blocks x 576 threads (9 waves): ~3 blocks/CU, ~27 waves/CU.

#define HH 32
#define WW 32
#define CC 27
#define OCC 27

// majority gate on s-domain values: ab + ac + bc - 2abc (3 VALU ops)
__device__ __forceinline__ float maj3(float a, float b, float c) {
    float ab = a * b;
    float t  = fmaf(-2.0f, ab, a + b);   // a + b - 2ab
    return fmaf(c, t, ab);               // ab + c*(a+b-2ab)
}

// tile: 27 ch x 10 rows x stride 36 (38,880 B), prescaled 0.5, pad -0.5.
// part: 9 groups x 256 px (9,216 B). Total LDS 48,096 B -> 3 blocks/CU.
__global__ __launch_bounds__(576, 7) void sconv_maj_kernel(
    const float* __restrict__ x, const float* __restrict__ w, float* __restrict__ out)
{
    __shared__ float tile[270 * 36];
    __shared__ float part[9 * 256];

    const int b    = blockIdx.x;
    const int rg   = b & 3;            // 4 row-groups of 8 output rows
    const int rest = b >> 2;
    const int oc   = rest % OCC;       // blockIdx-derived -> scalar weights
    const int n    = rest / OCC;
    const int tid  = threadIdx.x;

    const float* __restrict__ xb = x + n * (CC * HH * WW);

    // ---- stage prescaled, padded tile (all 576 threads) ----
    {
        const int lane = tid & 31;     // column 0..31
        const int team = tid >> 5;     // 18 row-teams
        for (int R = team; R < 270; R += 18) {    // R = c*10 + tr
            const int c  = R / 10;
            const int tr = R - c * 10;
            const int ih = rg * 8 + tr - 1;
            float v = -0.5f;
            if ((unsigned)ih < 32u) v = 0.5f * xb[c * (HH * WW) + ih * WW + lane];
            tile[R * 36 + 1 + lane] = v;
        }
        for (int i = tid; i < 540; i += 576) {    // col 0 / col 33 borders
            const int R = i >> 1;
            tile[R * 36 + ((i & 1) ? 33 : 0)] = -0.5f;
        }
    }
    __syncthreads();

    // ---- partial trees: wave g = (c3*3+c2); thread = 4 px in one row ----
    const int g   = __builtin_amdgcn_readfirstlane(tid >> 6);  // 0..8, SGPR
    const int lt  = tid & 63;
    const int pr  = lt >> 3;           // pixel row 0..7
    const int ow0 = (lt & 7) << 2;     // columns ow0..ow0+3 (16B-aligned)

    {
        const float* __restrict__ wp = w + oc * 243 + g * 27;  // 3 channels
        float p3[4][3];
#pragma unroll
        for (int c1 = 0; c1 < 3; ++c1) {
            const int c = g * 3 + c1;                 // = c3*9 + c2*3 + c1
            const float* trow = &tile[(c * 10 + pr) * 36 + ow0];
            float rr[4][3];
#pragma unroll
            for (int kh = 0; kh < 3; ++kh) {
                // 6 consecutive taps for 4 px: b128 (16B-aligned) + b64
                const float4 u = *(const float4*)(trow + kh * 36);
                const float2 v = *(const float2*)(trow + kh * 36 + 4);
                const float w0 = wp[c1 * 9 + kh * 3 + 0];
                const float w1 = wp[c1 * 9 + kh * 3 + 1];
                const float w2 = wp[c1 * 9 + kh * 3 + 2];
                // leaf s = (x*w+1)/2 = (0.5x)*w + 0.5; level 1: kw
                rr[0][kh] = maj3(fmaf(u.x, w0, 0.5f), fmaf(u.y, w1, 0.5f), fmaf(u.z, w2, 0.5f));
                rr[1][kh] = maj3(fmaf(u.y, w0, 0.5f), fmaf(u.z, w1, 0.5f), fmaf(u.w, w2, 0.5f));
                rr[2][kh] = maj3(fmaf(u.z, w0, 0.5f), fmaf(u.w, w1, 0.5f), fmaf(v.x, w2, 0.5f));
                rr[3][kh] = maj3(fmaf(u.w, w0, 0.5f), fmaf(v.x, w1, 0.5f), fmaf(v.y, w2, 0.5f));
            }
#pragma unroll
            for (int p = 0; p < 4; ++p)               // level 2: kh
                p3[p][c1] = maj3(rr[p][0], rr[p][1], rr[p][2]);
        }
        float4 o;                                     // level 3: c1 (partial)
        o.x = maj3(p3[0][0], p3[0][1], p3[0][2]);
        o.y = maj3(p3[1][0], p3[1][1], p3[1][2]);
        o.z = maj3(p3[2][0], p3[2][1], p3[2][2]);
        o.w = maj3(p3[3][0], p3[3][1], p3[3][2]);
        *(float4*)(&part[g * 256 + pr * 32 + ow0]) = o;   // aligned b128 write
    }
    __syncthreads();

    // ---- combine: level 4 (c2), level 5 (c3), back-convert; 256 threads ----
    if (tid < 256) {
        const int px = tid;
        const float m0 = maj3(part[0 * 256 + px], part[1 * 256 + px], part[2 * 256 + px]);
        const float m1 = maj3(part[3 * 256 + px], part[4 * 256 + px], part[5 * 256 + px]);
        const float m2 = maj3(part[6 * 256 + px], part[7 * 256 + px], part[8 * 256 + px]);
        const float y  = fmaf(2.0f, maj3(m0, m1, m2), -1.0f);
        const int oh = rg * 8 + (px >> 5);
        const int ow = px & 31;
        out[(((n * OCC + oc) * HH) + oh) * WW + ow] = y;
    }
}

extern "C" void kernel_launch(void* const* d_in, const int* in_sizes, int n_in,
                              void* d_out, int out_size, void* d_ws, size_t ws_size,
                              hipStream_t stream) {
    const float* x = (const float*)d_in[0];
    const float* w = (const float*)d_in[1];
    float* out = (float*)d_out;
    // grid: 8 n * 27 oc * 4 row-groups = 864 blocks, 576 threads (9 waves)
    sconv_maj_kernel<<<dim3(8 * OCC * 4), dim3(576), 0, stream>>>(x, w, out);
}